// Round 4
// baseline (245.942 us; speedup 1.0000x reference)
//
#include <hip/hip_runtime.h>

#define D_FEAT 128

typedef unsigned int u32;

__device__ __forceinline__ u32 f2bf_pack(float a, float b) {
    u32 ua = __float_as_uint(a);
    u32 ub = __float_as_uint(b);
    ua = (ua + 0x7fffu + ((ua >> 16) & 1u)) >> 16;   // RNE to bf16
    ub = (ub + 0x7fffu + ((ub >> 16) & 1u)) >> 16;
    return ua | (ub << 16);
}

// K1: hn[v,:] = bf16(h[v,:] * norm[v])  (packed 2/uint), and zero counts[].
__global__ void hn_pre(const float* __restrict__ h, const float* __restrict__ norm,
                       u32* __restrict__ hn, int* __restrict__ counts, int n_nodes) {
    int i = blockIdx.x * 256 + threadIdx.x;   // one thread per 4 features
    if (i < n_nodes) counts[i] = 0;
    int total = n_nodes * (D_FEAT / 4);
    if (i >= total) return;
    int node = i >> 5;                        // D_FEAT/4 = 32 threads per node
    float nm = norm[node];
    float4 v = reinterpret_cast<const float4*>(h)[i];
    uint2 o;
    o.x = f2bf_pack(v.x * nm, v.y * nm);
    o.y = f2bf_pack(v.z * nm, v.w * nm);
    reinterpret_cast<uint2*>(hn)[i] = o;
}

// K2: degree histogram
__global__ void deg_count(const int* __restrict__ dst, int* __restrict__ counts,
                          int n_edges) {
    int i = blockIdx.x * blockDim.x + threadIdx.x;
    if (i < n_edges) atomicAdd(&counts[dst[i]], 1);
}

// K3: single-kernel exclusive scan; 1024 threads, each owns a contiguous chunk.
__global__ void scan_single(const int* __restrict__ counts, int* __restrict__ offs,
                            int* __restrict__ cursor, int n) {
    __shared__ int smem[1024];
    int tid = threadIdx.x;
    int per = (n + 1023) >> 10;
    int beg = tid * per;
    int end = min(beg + per, n);
    int sum = 0;
    for (int i = beg; i < end; ++i) sum += counts[i];
    smem[tid] = sum;
    __syncthreads();
    for (int off = 1; off < 1024; off <<= 1) {
        int t = (tid >= off) ? smem[tid - off] : 0;
        __syncthreads();
        smem[tid] += t;
        __syncthreads();
    }
    int pre = smem[tid] - sum;               // exclusive prefix of this chunk
    for (int i = beg; i < end; ++i) {
        int v = counts[i];
        offs[i] = pre;
        cursor[i] = pre;
        pre += v;
    }
    if (tid == 1023) offs[n] = smem[1023];
}

// K4: bucket edges by dst
__global__ void scatter_csr(const int* __restrict__ src, const int* __restrict__ dst,
                            int* __restrict__ cursor, int* __restrict__ csr_src,
                            int n_edges) {
    int i = blockIdx.x * blockDim.x + threadIdx.x;
    if (i < n_edges) {
        int p = atomicAdd(&cursor[dst[i]], 1);
        csr_src[p] = src[i];
    }
}

// K5: one wave per node; gather bf16 rows (norm already folded in), fp32 accum.
__global__ void gather_bf16(const float* __restrict__ h,
                            const float* __restrict__ norm,
                            const float* __restrict__ eps,
                            const int* __restrict__ offs,
                            const int* __restrict__ csr_src,
                            const u32* __restrict__ hn,
                            float* __restrict__ out, int n_nodes) {
    int node = blockIdx.x * 4 + (threadIdx.x >> 6);
    int lane = threadIdx.x & 63;
    if (node >= n_nodes) return;
    int beg = offs[node];
    int end = offs[node + 1];
    float accx = 0.0f, accy = 0.0f;
    int i = beg;
    for (; i + 3 < end; i += 4) {
        int s0 = csr_src[i + 0];
        int s1 = csr_src[i + 1];
        int s2 = csr_src[i + 2];
        int s3 = csr_src[i + 3];
        u32 p0 = hn[s0 * 64 + lane];
        u32 p1 = hn[s1 * 64 + lane];
        u32 p2 = hn[s2 * 64 + lane];
        u32 p3 = hn[s3 * 64 + lane];
        accx += __uint_as_float(p0 << 16) + __uint_as_float(p1 << 16)
              + __uint_as_float(p2 << 16) + __uint_as_float(p3 << 16);
        accy += __uint_as_float(p0 & 0xffff0000u) + __uint_as_float(p1 & 0xffff0000u)
              + __uint_as_float(p2 & 0xffff0000u) + __uint_as_float(p3 & 0xffff0000u);
    }
    for (; i < end; ++i) {
        u32 p = hn[csr_src[i] * 64 + lane];
        accx += __uint_as_float(p << 16);
        accy += __uint_as_float(p & 0xffff0000u);
    }
    float nd = norm[node];
    float e1 = 1.0f + eps[0];
    float2 hv = *reinterpret_cast<const float2*>(h + (long long)node * D_FEAT + lane * 2);
    float2 o;
    o.x = (e1 * hv.x * nd + accx) * nd;
    o.y = (e1 * hv.y * nd + accy) * nd;
    *reinterpret_cast<float2*>(out + (long long)node * D_FEAT + lane * 2) = o;
}

// ---------- tier-2 fp32 gather (no hn staging) ----------
__global__ void gather_fp32(const float* __restrict__ h,
                            const float* __restrict__ norm,
                            const float* __restrict__ eps,
                            const int* __restrict__ offs,
                            const int* __restrict__ csr_src,
                            float* __restrict__ out, int n_nodes) {
    int node = blockIdx.x * 4 + (threadIdx.x >> 6);
    int lane = threadIdx.x & 63;
    if (node >= n_nodes) return;
    int beg = offs[node];
    int end = offs[node + 1];
    float accx = 0.0f, accy = 0.0f;
    int i = beg;
    for (; i + 3 < end; i += 4) {
        int s0 = csr_src[i + 0], s1 = csr_src[i + 1];
        int s2 = csr_src[i + 2], s3 = csr_src[i + 3];
        float n0 = norm[s0], n1 = norm[s1], n2 = norm[s2], n3 = norm[s3];
        float2 v0 = *reinterpret_cast<const float2*>(h + (long long)s0 * D_FEAT + lane * 2);
        float2 v1 = *reinterpret_cast<const float2*>(h + (long long)s1 * D_FEAT + lane * 2);
        float2 v2 = *reinterpret_cast<const float2*>(h + (long long)s2 * D_FEAT + lane * 2);
        float2 v3 = *reinterpret_cast<const float2*>(h + (long long)s3 * D_FEAT + lane * 2);
        accx += v0.x * n0 + v1.x * n1 + v2.x * n2 + v3.x * n3;
        accy += v0.y * n0 + v1.y * n1 + v2.y * n2 + v3.y * n3;
    }
    for (; i < end; ++i) {
        int s = csr_src[i];
        float ns = norm[s];
        float2 v = *reinterpret_cast<const float2*>(h + (long long)s * D_FEAT + lane * 2);
        accx += v.x * ns;
        accy += v.y * ns;
    }
    float nd = norm[node];
    float e1 = 1.0f + eps[0];
    float2 hv = *reinterpret_cast<const float2*>(h + (long long)node * D_FEAT + lane * 2);
    float2 o;
    o.x = (e1 * hv.x * nd + accx) * nd;
    o.y = (e1 * hv.y * nd + accy) * nd;
    *reinterpret_cast<float2*>(out + (long long)node * D_FEAT + lane * 2) = o;
}

// zero-counts helper for tier 2
__global__ void zero_counts(int* __restrict__ counts, int n) {
    int i = blockIdx.x * 256 + threadIdx.x;
    if (i < n) counts[i] = 0;
}

// ---------- tier-3 fallback (atomic scatter) ----------
__global__ void gin_init(const float* __restrict__ h, const float* __restrict__ norm,
                         const float* __restrict__ eps, float* __restrict__ out,
                         int n_nodes) {
    int i = blockIdx.x * blockDim.x + threadIdx.x;
    int total = n_nodes * (D_FEAT / 4);
    if (i >= total) return;
    int node = i / (D_FEAT / 4);
    float nm = norm[node];
    float scale = (1.0f + eps[0]) * nm * nm;
    const float4* h4 = reinterpret_cast<const float4*>(h);
    float4* o4 = reinterpret_cast<float4*>(out);
    float4 v = h4[i];
    v.x *= scale; v.y *= scale; v.z *= scale; v.w *= scale;
    o4[i] = v;
}

__global__ void gin_edge(const float* __restrict__ h, const float* __restrict__ norm,
                         const int* __restrict__ src, const int* __restrict__ dst,
                         float* __restrict__ out, int n_edges) {
    long long t = (long long)blockIdx.x * blockDim.x + threadIdx.x;
    int e = (int)(t >> 5);
    int lane = (int)(t & 31);
    if (e >= n_edges) return;
    int s = src[e], d = dst[e];
    float coef = norm[s] * norm[d];
    const float4* hs = reinterpret_cast<const float4*>(h + (long long)s * D_FEAT);
    float4 v = hs[lane];
    float* od = out + (long long)d * D_FEAT + lane * 4;
    atomicAdd(od + 0, v.x * coef);
    atomicAdd(od + 1, v.y * coef);
    atomicAdd(od + 2, v.z * coef);
    atomicAdd(od + 3, v.w * coef);
}

extern "C" void kernel_launch(void* const* d_in, const int* in_sizes, int n_in,
                              void* d_out, int out_size, void* d_ws, size_t ws_size,
                              hipStream_t stream) {
    const float* h    = (const float*)d_in[0];
    const float* norm = (const float*)d_in[1];
    const float* eps  = (const float*)d_in[2];
    const int*   src  = (const int*)d_in[3];
    const int*   dst  = (const int*)d_in[4];
    float* out = (float*)d_out;

    int n_nodes = in_sizes[1];
    int n_edges = in_sizes[3];

    size_t hn_words  = (size_t)n_nodes * (D_FEAT / 2);           // u32 per node-row
    size_t int_words = (size_t)(n_nodes + 1) + n_nodes + n_edges;
    size_t need1 = (hn_words + int_words) * 4;
    size_t need2 = int_words * 4;

    int eb = (n_edges + 255) / 256;
    int gb = (n_nodes + 3) / 4;

    if (ws_size >= need1) {
        u32* hn      = (u32*)d_ws;                   // n_nodes*64 words
        int* offs    = (int*)(hn + hn_words);        // n_nodes+1
        int* cursor  = offs + (n_nodes + 1);         // n_nodes (also counts)
        int* csr_src = cursor + n_nodes;             // n_edges

        int pre_threads = n_nodes * (D_FEAT / 4);
        hn_pre<<<(pre_threads + 255) / 256, 256, 0, stream>>>(h, norm, hn, cursor, n_nodes);
        deg_count<<<eb, 256, 0, stream>>>(dst, cursor, n_edges);
        scan_single<<<1, 1024, 0, stream>>>(cursor, offs, cursor, n_nodes);
        scatter_csr<<<eb, 256, 0, stream>>>(src, dst, cursor, csr_src, n_edges);
        gather_bf16<<<gb, 256, 0, stream>>>(h, norm, eps, offs, csr_src, hn, out, n_nodes);
    } else if (ws_size >= need2) {
        int* offs    = (int*)d_ws;
        int* cursor  = offs + (n_nodes + 1);
        int* csr_src = cursor + n_nodes;

        zero_counts<<<(n_nodes + 255) / 256, 256, 0, stream>>>(cursor, n_nodes);
        deg_count<<<eb, 256, 0, stream>>>(dst, cursor, n_edges);
        scan_single<<<1, 1024, 0, stream>>>(cursor, offs, cursor, n_nodes);
        scatter_csr<<<eb, 256, 0, stream>>>(src, dst, cursor, csr_src, n_edges);
        gather_fp32<<<gb, 256, 0, stream>>>(h, norm, eps, offs, csr_src, out, n_nodes);
    } else {
        int init_threads = n_nodes * (D_FEAT / 4);
        gin_init<<<(init_threads + 255) / 256, 256, 0, stream>>>(h, norm, eps, out, n_nodes);
        long long et = (long long)n_edges * 32;
        gin_edge<<<(int)((et + 255) / 256), 256, 0, stream>>>(h, norm, src, dst, out, n_edges);
    }
}

// Round 5
// 108.950 us; speedup vs baseline: 2.2574x; 2.2574x over previous
//
#include <hip/hip_runtime.h>

#define D_FEAT 128

typedef unsigned int u32;

__device__ __forceinline__ u32 f2bf_pack(float a, float b) {
    u32 ua = __float_as_uint(a);
    u32 ub = __float_as_uint(b);
    ua = (ua + 0x7fffu + ((ua >> 16) & 1u)) >> 16;   // RNE to bf16
    ub = (ub + 0x7fffu + ((ub >> 16) & 1u)) >> 16;
    return ua | (ub << 16);
}

// K1: hn[v,:] = bf16(h[v,:] * norm[v]) packed 2-per-u32, and zero counts[].
__global__ void hn_pre(const float* __restrict__ h, const float* __restrict__ norm,
                       u32* __restrict__ hn, int* __restrict__ counts, int n_nodes) {
    int i = blockIdx.x * 256 + threadIdx.x;   // one thread per 4 features
    if (i < n_nodes) counts[i] = 0;
    int total = n_nodes * (D_FEAT / 4);
    if (i >= total) return;
    int node = i >> 5;                        // 32 threads per node
    float nm = norm[node];
    float4 v = reinterpret_cast<const float4*>(h)[i];
    uint2 o;
    o.x = f2bf_pack(v.x * nm, v.y * nm);
    o.y = f2bf_pack(v.z * nm, v.w * nm);
    reinterpret_cast<uint2*>(hn)[i] = o;
}

// K2a: histogram + per-edge bucket rank (tier A)
__global__ void deg_rank(const int* __restrict__ dst, int* __restrict__ counts,
                         int* __restrict__ rank, int n_edges) {
    int i = blockIdx.x * blockDim.x + threadIdx.x;
    if (i < n_edges) rank[i] = atomicAdd(&counts[dst[i]], 1);
}

// K2b: histogram only (tier B)
__global__ void deg_count(const int* __restrict__ dst, int* __restrict__ counts,
                          int n_edges) {
    int i = blockIdx.x * blockDim.x + threadIdx.x;
    if (i < n_edges) atomicAdd(&counts[dst[i]], 1);
}

// hierarchical scan, stage 1: per-block (1024 elems) local exclusive scan
__global__ void scan_local(const int* __restrict__ counts, int* __restrict__ offs,
                           int* __restrict__ blocksums, int n) {
    int tid = threadIdx.x;
    int base = blockIdx.x * 1024 + tid * 4;
    int v0 = (base + 0 < n) ? counts[base + 0] : 0;
    int v1 = (base + 1 < n) ? counts[base + 1] : 0;
    int v2 = (base + 2 < n) ? counts[base + 2] : 0;
    int v3 = (base + 3 < n) ? counts[base + 3] : 0;
    int tsum = v0 + v1 + v2 + v3;
    __shared__ int smem[256];
    smem[tid] = tsum;
    __syncthreads();
    for (int off = 1; off < 256; off <<= 1) {
        int t = (tid >= off) ? smem[tid - off] : 0;
        __syncthreads();
        smem[tid] += t;
        __syncthreads();
    }
    int ex = smem[tid] - tsum;
    if (base + 0 < n) offs[base + 0] = ex;
    if (base + 1 < n) offs[base + 1] = ex + v0;
    if (base + 2 < n) offs[base + 2] = ex + v0 + v1;
    if (base + 3 < n) offs[base + 3] = ex + v0 + v1 + v2;
    if (tid == 255) blocksums[blockIdx.x] = smem[255];
}

// stage 2: exclusive-scan block sums in place; also writes offs[n] = total
__global__ void scan_blocksums(int* __restrict__ blocksums, int* __restrict__ offs,
                               int nb, int n) {
    __shared__ int smem[256];
    __shared__ int carry_s;
    int tid = threadIdx.x;
    if (tid == 0) carry_s = 0;
    __syncthreads();
    for (int basei = 0; basei < nb; basei += 256) {
        int i = basei + tid;
        int v = (i < nb) ? blocksums[i] : 0;
        smem[tid] = v;
        __syncthreads();
        for (int off = 1; off < 256; off <<= 1) {
            int t = (tid >= off) ? smem[tid - off] : 0;
            __syncthreads();
            smem[tid] += t;
            __syncthreads();
        }
        int carry = carry_s;
        if (i < nb) blocksums[i] = carry + smem[tid] - v;
        __syncthreads();
        if (tid == 255) carry_s = carry + smem[255];
        __syncthreads();
    }
    if (tid == 0) offs[n] = carry_s;
}

// stage 3: add block offsets; optionally mirror into cursor
__global__ void add_back(int* __restrict__ offs, int* __restrict__ cursor,
                         const int* __restrict__ blocksums, int n) {
    int i = blockIdx.x * 256 + threadIdx.x;
    if (i < n) {
        int v = offs[i] + blocksums[i >> 10];
        offs[i] = v;
        if (cursor) cursor[i] = v;
    }
}

// K4a: atomic-free scatter using precomputed ranks (tier A)
__global__ void scatter_rank(const int* __restrict__ src, const int* __restrict__ dst,
                             const int* __restrict__ offs, const int* __restrict__ rank,
                             int* __restrict__ csr_src, int n_edges) {
    int i = blockIdx.x * blockDim.x + threadIdx.x;
    if (i < n_edges) csr_src[offs[dst[i]] + rank[i]] = src[i];
}

// K4b: atomic-cursor scatter (tier B)
__global__ void scatter_csr(const int* __restrict__ src, const int* __restrict__ dst,
                            int* __restrict__ cursor, int* __restrict__ csr_src,
                            int n_edges) {
    int i = blockIdx.x * blockDim.x + threadIdx.x;
    if (i < n_edges) {
        int p = atomicAdd(&cursor[dst[i]], 1);
        csr_src[p] = src[i];
    }
}

// K5: one wave per node; gather bf16 rows (norm folded in), fp32 accum.
__global__ void gather_bf16(const float* __restrict__ h,
                            const float* __restrict__ norm,
                            const float* __restrict__ eps,
                            const int* __restrict__ offs,
                            const int* __restrict__ csr_src,
                            const u32* __restrict__ hn,
                            float* __restrict__ out, int n_nodes) {
    int node = blockIdx.x * 4 + (threadIdx.x >> 6);
    int lane = threadIdx.x & 63;
    if (node >= n_nodes) return;
    int beg = offs[node];
    int end = offs[node + 1];
    float accx = 0.0f, accy = 0.0f;
    int i = beg;
    for (; i + 3 < end; i += 4) {
        int s0 = csr_src[i + 0];
        int s1 = csr_src[i + 1];
        int s2 = csr_src[i + 2];
        int s3 = csr_src[i + 3];
        u32 p0 = hn[s0 * 64 + lane];
        u32 p1 = hn[s1 * 64 + lane];
        u32 p2 = hn[s2 * 64 + lane];
        u32 p3 = hn[s3 * 64 + lane];
        accx += __uint_as_float(p0 << 16) + __uint_as_float(p1 << 16)
              + __uint_as_float(p2 << 16) + __uint_as_float(p3 << 16);
        accy += __uint_as_float(p0 & 0xffff0000u) + __uint_as_float(p1 & 0xffff0000u)
              + __uint_as_float(p2 & 0xffff0000u) + __uint_as_float(p3 & 0xffff0000u);
    }
    for (; i < end; ++i) {
        u32 p = hn[csr_src[i] * 64 + lane];
        accx += __uint_as_float(p << 16);
        accy += __uint_as_float(p & 0xffff0000u);
    }
    float nd = norm[node];
    float e1 = 1.0f + eps[0];
    float2 hv = *reinterpret_cast<const float2*>(h + (long long)node * D_FEAT + lane * 2);
    float2 o;
    o.x = (e1 * hv.x * nd + accx) * nd;
    o.y = (e1 * hv.y * nd + accy) * nd;
    *reinterpret_cast<float2*>(out + (long long)node * D_FEAT + lane * 2) = o;
}

// ---------- tier-C fp32 gather (no hn staging) ----------
__global__ void gather_fp32(const float* __restrict__ h,
                            const float* __restrict__ norm,
                            const float* __restrict__ eps,
                            const int* __restrict__ offs,
                            const int* __restrict__ csr_src,
                            float* __restrict__ out, int n_nodes) {
    int node = blockIdx.x * 4 + (threadIdx.x >> 6);
    int lane = threadIdx.x & 63;
    if (node >= n_nodes) return;
    int beg = offs[node];
    int end = offs[node + 1];
    float accx = 0.0f, accy = 0.0f;
    int i = beg;
    for (; i + 3 < end; i += 4) {
        int s0 = csr_src[i + 0], s1 = csr_src[i + 1];
        int s2 = csr_src[i + 2], s3 = csr_src[i + 3];
        float n0 = norm[s0], n1 = norm[s1], n2 = norm[s2], n3 = norm[s3];
        float2 v0 = *reinterpret_cast<const float2*>(h + (long long)s0 * D_FEAT + lane * 2);
        float2 v1 = *reinterpret_cast<const float2*>(h + (long long)s1 * D_FEAT + lane * 2);
        float2 v2 = *reinterpret_cast<const float2*>(h + (long long)s2 * D_FEAT + lane * 2);
        float2 v3 = *reinterpret_cast<const float2*>(h + (long long)s3 * D_FEAT + lane * 2);
        accx += v0.x * n0 + v1.x * n1 + v2.x * n2 + v3.x * n3;
        accy += v0.y * n0 + v1.y * n1 + v2.y * n2 + v3.y * n3;
    }
    for (; i < end; ++i) {
        int s = csr_src[i];
        float ns = norm[s];
        float2 v = *reinterpret_cast<const float2*>(h + (long long)s * D_FEAT + lane * 2);
        accx += v.x * ns;
        accy += v.y * ns;
    }
    float nd = norm[node];
    float e1 = 1.0f + eps[0];
    float2 hv = *reinterpret_cast<const float2*>(h + (long long)node * D_FEAT + lane * 2);
    float2 o;
    o.x = (e1 * hv.x * nd + accx) * nd;
    o.y = (e1 * hv.y * nd + accy) * nd;
    *reinterpret_cast<float2*>(out + (long long)node * D_FEAT + lane * 2) = o;
}

__global__ void zero_counts(int* __restrict__ counts, int n) {
    int i = blockIdx.x * 256 + threadIdx.x;
    if (i < n) counts[i] = 0;
}

// ---------- tier-D fallback (atomic scatter) ----------
__global__ void gin_init(const float* __restrict__ h, const float* __restrict__ norm,
                         const float* __restrict__ eps, float* __restrict__ out,
                         int n_nodes) {
    int i = blockIdx.x * blockDim.x + threadIdx.x;
    int total = n_nodes * (D_FEAT / 4);
    if (i >= total) return;
    int node = i / (D_FEAT / 4);
    float nm = norm[node];
    float scale = (1.0f + eps[0]) * nm * nm;
    const float4* h4 = reinterpret_cast<const float4*>(h);
    float4* o4 = reinterpret_cast<float4*>(out);
    float4 v = h4[i];
    v.x *= scale; v.y *= scale; v.z *= scale; v.w *= scale;
    o4[i] = v;
}

__global__ void gin_edge(const float* __restrict__ h, const float* __restrict__ norm,
                         const int* __restrict__ src, const int* __restrict__ dst,
                         float* __restrict__ out, int n_edges) {
    long long t = (long long)blockIdx.x * blockDim.x + threadIdx.x;
    int e = (int)(t >> 5);
    int lane = (int)(t & 31);
    if (e >= n_edges) return;
    int s = src[e], d = dst[e];
    float coef = norm[s] * norm[d];
    const float4* hs = reinterpret_cast<const float4*>(h + (long long)s * D_FEAT);
    float4 v = hs[lane];
    float* od = out + (long long)d * D_FEAT + lane * 4;
    atomicAdd(od + 0, v.x * coef);
    atomicAdd(od + 1, v.y * coef);
    atomicAdd(od + 2, v.z * coef);
    atomicAdd(od + 3, v.w * coef);
}

extern "C" void kernel_launch(void* const* d_in, const int* in_sizes, int n_in,
                              void* d_out, int out_size, void* d_ws, size_t ws_size,
                              hipStream_t stream) {
    const float* h    = (const float*)d_in[0];
    const float* norm = (const float*)d_in[1];
    const float* eps  = (const float*)d_in[2];
    const int*   src  = (const int*)d_in[3];
    const int*   dst  = (const int*)d_in[4];
    float* out = (float*)d_out;

    int n_nodes = in_sizes[1];
    int n_edges = in_sizes[3];
    int nb = (n_nodes + 1023) / 1024;

    size_t hn_words = (size_t)n_nodes * (D_FEAT / 2);
    // tier A: hn + counts + offs + rank + csr_src + blocksums
    size_t needA = (hn_words + (size_t)n_nodes + (n_nodes + 1)
                    + 2 * (size_t)n_edges + nb) * 4;
    // tier B: hn + cursor/counts + offs + csr_src + blocksums
    size_t needB = (hn_words + (size_t)n_nodes + (n_nodes + 1)
                    + (size_t)n_edges + nb) * 4;
    // tier C: cursor/counts + offs + csr_src + blocksums (fp32 gather)
    size_t needC = ((size_t)n_nodes + (n_nodes + 1) + (size_t)n_edges + nb) * 4;

    int eb = (n_edges + 255) / 256;
    int gb = (n_nodes + 3) / 4;
    int pre_threads = n_nodes * (D_FEAT / 4);
    int ab = (n_nodes + 255) / 256;

    if (ws_size >= needA) {
        u32* hn        = (u32*)d_ws;
        int* counts    = (int*)(hn + hn_words);    // n_nodes
        int* offs      = counts + n_nodes;         // n_nodes+1
        int* rank      = offs + (n_nodes + 1);     // n_edges
        int* csr_src   = rank + n_edges;           // n_edges
        int* blocksums = csr_src + n_edges;        // nb

        hn_pre<<<(pre_threads + 255) / 256, 256, 0, stream>>>(h, norm, hn, counts, n_nodes);
        deg_rank<<<eb, 256, 0, stream>>>(dst, counts, rank, n_edges);
        scan_local<<<nb, 256, 0, stream>>>(counts, offs, blocksums, n_nodes);
        scan_blocksums<<<1, 256, 0, stream>>>(blocksums, offs, nb, n_nodes);
        add_back<<<ab, 256, 0, stream>>>(offs, nullptr, blocksums, n_nodes);
        scatter_rank<<<eb, 256, 0, stream>>>(src, dst, offs, rank, csr_src, n_edges);
        gather_bf16<<<gb, 256, 0, stream>>>(h, norm, eps, offs, csr_src, hn, out, n_nodes);
    } else if (ws_size >= needB) {
        u32* hn        = (u32*)d_ws;
        int* cursor    = (int*)(hn + hn_words);    // n_nodes (also counts)
        int* offs      = cursor + n_nodes;         // n_nodes+1
        int* csr_src   = offs + (n_nodes + 1);     // n_edges
        int* blocksums = csr_src + n_edges;        // nb

        hn_pre<<<(pre_threads + 255) / 256, 256, 0, stream>>>(h, norm, hn, cursor, n_nodes);
        deg_count<<<eb, 256, 0, stream>>>(dst, cursor, n_edges);
        scan_local<<<nb, 256, 0, stream>>>(cursor, offs, blocksums, n_nodes);
        scan_blocksums<<<1, 256, 0, stream>>>(blocksums, offs, nb, n_nodes);
        add_back<<<ab, 256, 0, stream>>>(offs, cursor, blocksums, n_nodes);
        scatter_csr<<<eb, 256, 0, stream>>>(src, dst, cursor, csr_src, n_edges);
        gather_bf16<<<gb, 256, 0, stream>>>(h, norm, eps, offs, csr_src, hn, out, n_nodes);
    } else if (ws_size >= needC) {
        int* cursor    = (int*)d_ws;
        int* offs      = cursor + n_nodes;
        int* csr_src   = offs + (n_nodes + 1);
        int* blocksums = csr_src + n_edges;

        zero_counts<<<ab, 256, 0, stream>>>(cursor, n_nodes);
        deg_count<<<eb, 256, 0, stream>>>(dst, cursor, n_edges);
        scan_local<<<nb, 256, 0, stream>>>(cursor, offs, blocksums, n_nodes);
        scan_blocksums<<<1, 256, 0, stream>>>(blocksums, offs, nb, n_nodes);
        add_back<<<ab, 256, 0, stream>>>(offs, cursor, blocksums, n_nodes);
        scatter_csr<<<eb, 256, 0, stream>>>(src, dst, cursor, csr_src, n_edges);
        gather_fp32<<<gb, 256, 0, stream>>>(h, norm, eps, offs, csr_src, out, n_nodes);
    } else {
        gin_init<<<(pre_threads + 255) / 256, 256, 0, stream>>>(h, norm, eps, out, n_nodes);
        long long et = (long long)n_edges * 32;
        gin_edge<<<(int)((et + 255) / 256), 256, 0, stream>>>(h, norm, src, dst, out, n_edges);
    }
}

// Round 6
// 101.864 us; speedup vs baseline: 2.4144x; 1.0696x over previous
//
#include <hip/hip_runtime.h>

#define D_FEAT 128

typedef unsigned int u32;

__device__ __forceinline__ u32 f2bf_pack(float a, float b) {
    u32 ua = __float_as_uint(a);
    u32 ub = __float_as_uint(b);
    ua = (ua + 0x7fffu + ((ua >> 16) & 1u)) >> 16;   // RNE to bf16
    ub = (ub + 0x7fffu + ((ub >> 16) & 1u)) >> 16;
    return ua | (ub << 16);
}

__device__ __forceinline__ float bf_lo(u32 p) { return __uint_as_float(p << 16); }
__device__ __forceinline__ float bf_hi(u32 p) { return __uint_as_float(p & 0xffff0000u); }

// K1: hn[v,:] = bf16(h[v,:] * norm[v]) packed 2-per-u32, and zero counts[].
__global__ void hn_pre(const float* __restrict__ h, const float* __restrict__ norm,
                       u32* __restrict__ hn, int* __restrict__ counts, int n_nodes) {
    int i = blockIdx.x * 256 + threadIdx.x;   // one thread per 4 features
    if (i < n_nodes) counts[i] = 0;
    int total = n_nodes * (D_FEAT / 4);
    if (i >= total) return;
    int node = i >> 5;                        // 32 threads per node
    float nm = norm[node];
    float4 v = reinterpret_cast<const float4*>(h)[i];
    uint2 o;
    o.x = f2bf_pack(v.x * nm, v.y * nm);
    o.y = f2bf_pack(v.z * nm, v.w * nm);
    reinterpret_cast<uint2*>(hn)[i] = o;
}

// K2a: histogram + per-edge bucket rank (tier A)
__global__ void deg_rank(const int* __restrict__ dst, int* __restrict__ counts,
                         int* __restrict__ rank, int n_edges) {
    int i = blockIdx.x * blockDim.x + threadIdx.x;
    if (i < n_edges) rank[i] = atomicAdd(&counts[dst[i]], 1);
}

// K2b: histogram only (tier B/C)
__global__ void deg_count(const int* __restrict__ dst, int* __restrict__ counts,
                          int n_edges) {
    int i = blockIdx.x * blockDim.x + threadIdx.x;
    if (i < n_edges) atomicAdd(&counts[dst[i]], 1);
}

// scan stage 1: per-block (1024 elems) LOCAL exclusive scan (no global offset)
__global__ void scan_local(const int* __restrict__ counts, int* __restrict__ offs,
                           int* __restrict__ blocksums, int n) {
    int tid = threadIdx.x;
    int base = blockIdx.x * 1024 + tid * 4;
    int v0 = (base + 0 < n) ? counts[base + 0] : 0;
    int v1 = (base + 1 < n) ? counts[base + 1] : 0;
    int v2 = (base + 2 < n) ? counts[base + 2] : 0;
    int v3 = (base + 3 < n) ? counts[base + 3] : 0;
    int tsum = v0 + v1 + v2 + v3;
    __shared__ int smem[256];
    smem[tid] = tsum;
    __syncthreads();
    for (int off = 1; off < 256; off <<= 1) {
        int t = (tid >= off) ? smem[tid - off] : 0;
        __syncthreads();
        smem[tid] += t;
        __syncthreads();
    }
    int ex = smem[tid] - tsum;
    if (base + 0 < n) offs[base + 0] = ex;
    if (base + 1 < n) offs[base + 1] = ex + v0;
    if (base + 2 < n) offs[base + 2] = ex + v0 + v1;
    if (base + 3 < n) offs[base + 3] = ex + v0 + v1 + v2;
    if (tid == 255) blocksums[blockIdx.x] = smem[255];
}

// scan stage 2: exclusive-scan block sums in place; writes offs[n] = total (final)
__global__ void scan_blocksums(int* __restrict__ blocksums, int* __restrict__ offs,
                               int nb, int n) {
    __shared__ int smem[256];
    __shared__ int carry_s;
    int tid = threadIdx.x;
    if (tid == 0) carry_s = 0;
    __syncthreads();
    for (int basei = 0; basei < nb; basei += 256) {
        int i = basei + tid;
        int v = (i < nb) ? blocksums[i] : 0;
        smem[tid] = v;
        __syncthreads();
        for (int off = 1; off < 256; off <<= 1) {
            int t = (tid >= off) ? smem[tid - off] : 0;
            __syncthreads();
            smem[tid] += t;
            __syncthreads();
        }
        int carry = carry_s;
        if (i < nb) blocksums[i] = carry + smem[tid] - v;
        __syncthreads();
        if (tid == 255) carry_s = carry + smem[255];
        __syncthreads();
    }
    if (tid == 0) offs[n] = carry_s;
}

// stage 3 (tiers B/C only): finalize offs and mirror into cursor
__global__ void add_back(int* __restrict__ offs, int* __restrict__ cursor,
                         const int* __restrict__ blocksums, int n) {
    int i = blockIdx.x * 256 + threadIdx.x;
    if (i < n) {
        int v = offs[i] + blocksums[i >> 10];
        offs[i] = v;
        if (cursor) cursor[i] = v;
    }
}

// K4a (tier A): atomic-free scatter; final offset = local offs + blocksum + rank
__global__ void scatter_rank(const int* __restrict__ src, const int* __restrict__ dst,
                             const int* __restrict__ offs, const int* __restrict__ bsums,
                             const int* __restrict__ rank,
                             int* __restrict__ csr_src, int n_edges) {
    int i = blockIdx.x * blockDim.x + threadIdx.x;
    if (i < n_edges) {
        int d = dst[i];
        csr_src[offs[d] + bsums[d >> 10] + rank[i]] = src[i];
    }
}

// K4b (tier B/C): atomic-cursor scatter
__global__ void scatter_csr(const int* __restrict__ src, const int* __restrict__ dst,
                            int* __restrict__ cursor, int* __restrict__ csr_src,
                            int n_edges) {
    int i = blockIdx.x * blockDim.x + threadIdx.x;
    if (i < n_edges) {
        int p = atomicAdd(&cursor[dst[i]], 1);
        csr_src[p] = src[i];
    }
}

// K5 (tier A): 32 lanes per node (2 nodes per wave), uint2 per lane (full 256B
// row per instruction), unroll-4 -> 8 independent row-loads in flight per wave.
__global__ void gather_bf16_v2(const float* __restrict__ h,
                               const float* __restrict__ norm,
                               const float* __restrict__ eps,
                               const int* __restrict__ offs,
                               const int* __restrict__ bsums,
                               const int* __restrict__ csr_src,
                               const u32* __restrict__ hn,
                               float* __restrict__ out, int n_nodes) {
    int t = blockIdx.x * 256 + threadIdx.x;
    int node = t >> 5;                       // 8 nodes per block
    int lane = t & 31;
    if (node >= n_nodes) return;
    int beg = offs[node] + bsums[node >> 10];
    int end = (node + 1 < n_nodes) ? (offs[node + 1] + bsums[(node + 1) >> 10])
                                   : offs[n_nodes];
    float a0 = 0.0f, a1 = 0.0f, a2 = 0.0f, a3 = 0.0f;
    int i = beg;
    for (; i + 4 <= end; i += 4) {
        int s0 = csr_src[i + 0];
        int s1 = csr_src[i + 1];
        int s2 = csr_src[i + 2];
        int s3 = csr_src[i + 3];
        uint2 p0 = reinterpret_cast<const uint2*>(hn + (size_t)s0 * 64)[lane];
        uint2 p1 = reinterpret_cast<const uint2*>(hn + (size_t)s1 * 64)[lane];
        uint2 p2 = reinterpret_cast<const uint2*>(hn + (size_t)s2 * 64)[lane];
        uint2 p3 = reinterpret_cast<const uint2*>(hn + (size_t)s3 * 64)[lane];
        a0 += bf_lo(p0.x) + bf_lo(p1.x) + bf_lo(p2.x) + bf_lo(p3.x);
        a1 += bf_hi(p0.x) + bf_hi(p1.x) + bf_hi(p2.x) + bf_hi(p3.x);
        a2 += bf_lo(p0.y) + bf_lo(p1.y) + bf_lo(p2.y) + bf_lo(p3.y);
        a3 += bf_hi(p0.y) + bf_hi(p1.y) + bf_hi(p2.y) + bf_hi(p3.y);
    }
    for (; i < end; ++i) {
        uint2 p = reinterpret_cast<const uint2*>(hn + (size_t)csr_src[i] * 64)[lane];
        a0 += bf_lo(p.x); a1 += bf_hi(p.x); a2 += bf_lo(p.y); a3 += bf_hi(p.y);
    }
    float nd = norm[node];
    float e1 = 1.0f + eps[0];
    float4 hv = reinterpret_cast<const float4*>(h + (size_t)node * D_FEAT)[lane];
    float4 o;
    o.x = (e1 * hv.x * nd + a0) * nd;
    o.y = (e1 * hv.y * nd + a1) * nd;
    o.z = (e1 * hv.z * nd + a2) * nd;
    o.w = (e1 * hv.w * nd + a3) * nd;
    reinterpret_cast<float4*>(out + (size_t)node * D_FEAT)[lane] = o;
}

// tier-B gather (final offs, one wave per node)
__global__ void gather_bf16(const float* __restrict__ h, const float* __restrict__ norm,
                            const float* __restrict__ eps, const int* __restrict__ offs,
                            const int* __restrict__ csr_src, const u32* __restrict__ hn,
                            float* __restrict__ out, int n_nodes) {
    int node = blockIdx.x * 4 + (threadIdx.x >> 6);
    int lane = threadIdx.x & 63;
    if (node >= n_nodes) return;
    int beg = offs[node];
    int end = offs[node + 1];
    float accx = 0.0f, accy = 0.0f;
    int i = beg;
    for (; i + 3 < end; i += 4) {
        int s0 = csr_src[i + 0], s1 = csr_src[i + 1];
        int s2 = csr_src[i + 2], s3 = csr_src[i + 3];
        u32 p0 = hn[s0 * 64 + lane];
        u32 p1 = hn[s1 * 64 + lane];
        u32 p2 = hn[s2 * 64 + lane];
        u32 p3 = hn[s3 * 64 + lane];
        accx += bf_lo(p0) + bf_lo(p1) + bf_lo(p2) + bf_lo(p3);
        accy += bf_hi(p0) + bf_hi(p1) + bf_hi(p2) + bf_hi(p3);
    }
    for (; i < end; ++i) {
        u32 p = hn[csr_src[i] * 64 + lane];
        accx += bf_lo(p);
        accy += bf_hi(p);
    }
    float nd = norm[node];
    float e1 = 1.0f + eps[0];
    float2 hv = *reinterpret_cast<const float2*>(h + (long long)node * D_FEAT + lane * 2);
    float2 o;
    o.x = (e1 * hv.x * nd + accx) * nd;
    o.y = (e1 * hv.y * nd + accy) * nd;
    *reinterpret_cast<float2*>(out + (long long)node * D_FEAT + lane * 2) = o;
}

// tier-C fp32 gather (no hn staging)
__global__ void gather_fp32(const float* __restrict__ h, const float* __restrict__ norm,
                            const float* __restrict__ eps, const int* __restrict__ offs,
                            const int* __restrict__ csr_src, float* __restrict__ out,
                            int n_nodes) {
    int node = blockIdx.x * 4 + (threadIdx.x >> 6);
    int lane = threadIdx.x & 63;
    if (node >= n_nodes) return;
    int beg = offs[node];
    int end = offs[node + 1];
    float accx = 0.0f, accy = 0.0f;
    int i = beg;
    for (; i + 3 < end; i += 4) {
        int s0 = csr_src[i + 0], s1 = csr_src[i + 1];
        int s2 = csr_src[i + 2], s3 = csr_src[i + 3];
        float n0 = norm[s0], n1 = norm[s1], n2 = norm[s2], n3 = norm[s3];
        float2 v0 = *reinterpret_cast<const float2*>(h + (long long)s0 * D_FEAT + lane * 2);
        float2 v1 = *reinterpret_cast<const float2*>(h + (long long)s1 * D_FEAT + lane * 2);
        float2 v2 = *reinterpret_cast<const float2*>(h + (long long)s2 * D_FEAT + lane * 2);
        float2 v3 = *reinterpret_cast<const float2*>(h + (long long)s3 * D_FEAT + lane * 2);
        accx += v0.x * n0 + v1.x * n1 + v2.x * n2 + v3.x * n3;
        accy += v0.y * n0 + v1.y * n1 + v2.y * n2 + v3.y * n3;
    }
    for (; i < end; ++i) {
        int s = csr_src[i];
        float ns = norm[s];
        float2 v = *reinterpret_cast<const float2*>(h + (long long)s * D_FEAT + lane * 2);
        accx += v.x * ns;
        accy += v.y * ns;
    }
    float nd = norm[node];
    float e1 = 1.0f + eps[0];
    float2 hv = *reinterpret_cast<const float2*>(h + (long long)node * D_FEAT + lane * 2);
    float2 o;
    o.x = (e1 * hv.x * nd + accx) * nd;
    o.y = (e1 * hv.y * nd + accy) * nd;
    *reinterpret_cast<float2*>(out + (long long)node * D_FEAT + lane * 2) = o;
}

__global__ void zero_counts(int* __restrict__ counts, int n) {
    int i = blockIdx.x * 256 + threadIdx.x;
    if (i < n) counts[i] = 0;
}

// ---------- tier-D fallback (atomic scatter) ----------
__global__ void gin_init(const float* __restrict__ h, const float* __restrict__ norm,
                         const float* __restrict__ eps, float* __restrict__ out,
                         int n_nodes) {
    int i = blockIdx.x * blockDim.x + threadIdx.x;
    int total = n_nodes * (D_FEAT / 4);
    if (i >= total) return;
    int node = i / (D_FEAT / 4);
    float nm = norm[node];
    float scale = (1.0f + eps[0]) * nm * nm;
    const float4* h4 = reinterpret_cast<const float4*>(h);
    float4* o4 = reinterpret_cast<float4*>(out);
    float4 v = h4[i];
    v.x *= scale; v.y *= scale; v.z *= scale; v.w *= scale;
    o4[i] = v;
}

__global__ void gin_edge(const float* __restrict__ h, const float* __restrict__ norm,
                         const int* __restrict__ src, const int* __restrict__ dst,
                         float* __restrict__ out, int n_edges) {
    long long t = (long long)blockIdx.x * blockDim.x + threadIdx.x;
    int e = (int)(t >> 5);
    int lane = (int)(t & 31);
    if (e >= n_edges) return;
    int s = src[e], d = dst[e];
    float coef = norm[s] * norm[d];
    const float4* hs = reinterpret_cast<const float4*>(h + (long long)s * D_FEAT);
    float4 v = hs[lane];
    float* od = out + (long long)d * D_FEAT + lane * 4;
    atomicAdd(od + 0, v.x * coef);
    atomicAdd(od + 1, v.y * coef);
    atomicAdd(od + 2, v.z * coef);
    atomicAdd(od + 3, v.w * coef);
}

extern "C" void kernel_launch(void* const* d_in, const int* in_sizes, int n_in,
                              void* d_out, int out_size, void* d_ws, size_t ws_size,
                              hipStream_t stream) {
    const float* h    = (const float*)d_in[0];
    const float* norm = (const float*)d_in[1];
    const float* eps  = (const float*)d_in[2];
    const int*   src  = (const int*)d_in[3];
    const int*   dst  = (const int*)d_in[4];
    float* out = (float*)d_out;

    int n_nodes = in_sizes[1];
    int n_edges = in_sizes[3];
    int nb = (n_nodes + 1023) / 1024;

    size_t hn_words = (size_t)n_nodes * (D_FEAT / 2);
    size_t needA = (hn_words + (size_t)n_nodes + (n_nodes + 1)
                    + 2 * (size_t)n_edges + nb) * 4;
    size_t needB = (hn_words + (size_t)n_nodes + (n_nodes + 1)
                    + (size_t)n_edges + nb) * 4;
    size_t needC = ((size_t)n_nodes + (n_nodes + 1) + (size_t)n_edges + nb) * 4;

    int eb = (n_edges + 255) / 256;
    int pre_threads = n_nodes * (D_FEAT / 4);
    int ab = (n_nodes + 255) / 256;

    if (ws_size >= needA) {
        u32* hn        = (u32*)d_ws;
        int* counts    = (int*)(hn + hn_words);    // n_nodes
        int* offs      = counts + n_nodes;         // n_nodes+1 (LOCAL prefixes)
        int* rank      = offs + (n_nodes + 1);     // n_edges
        int* csr_src   = rank + n_edges;           // n_edges
        int* blocksums = csr_src + n_edges;        // nb

        hn_pre<<<(pre_threads + 255) / 256, 256, 0, stream>>>(h, norm, hn, counts, n_nodes);
        deg_rank<<<eb, 256, 0, stream>>>(dst, counts, rank, n_edges);
        scan_local<<<nb, 256, 0, stream>>>(counts, offs, blocksums, n_nodes);
        scan_blocksums<<<1, 256, 0, stream>>>(blocksums, offs, nb, n_nodes);
        scatter_rank<<<eb, 256, 0, stream>>>(src, dst, offs, blocksums, rank, csr_src, n_edges);
        int gb2 = (n_nodes + 7) / 8;
        gather_bf16_v2<<<gb2, 256, 0, stream>>>(h, norm, eps, offs, blocksums,
                                                csr_src, hn, out, n_nodes);
    } else if (ws_size >= needB) {
        u32* hn        = (u32*)d_ws;
        int* cursor    = (int*)(hn + hn_words);
        int* offs      = cursor + n_nodes;
        int* csr_src   = offs + (n_nodes + 1);
        int* blocksums = csr_src + n_edges;

        hn_pre<<<(pre_threads + 255) / 256, 256, 0, stream>>>(h, norm, hn, cursor, n_nodes);
        deg_count<<<eb, 256, 0, stream>>>(dst, cursor, n_edges);
        scan_local<<<nb, 256, 0, stream>>>(cursor, offs, blocksums, n_nodes);
        scan_blocksums<<<1, 256, 0, stream>>>(blocksums, offs, nb, n_nodes);
        add_back<<<ab, 256, 0, stream>>>(offs, cursor, blocksums, n_nodes);
        scatter_csr<<<eb, 256, 0, stream>>>(src, dst, cursor, csr_src, n_edges);
        int gb = (n_nodes + 3) / 4;
        gather_bf16<<<gb, 256, 0, stream>>>(h, norm, eps, offs, csr_src, hn, out, n_nodes);
    } else if (ws_size >= needC) {
        int* cursor    = (int*)d_ws;
        int* offs      = cursor + n_nodes;
        int* csr_src   = offs + (n_nodes + 1);
        int* blocksums = csr_src + n_edges;

        zero_counts<<<ab, 256, 0, stream>>>(cursor, n_nodes);
        deg_count<<<eb, 256, 0, stream>>>(dst, cursor, n_edges);
        scan_local<<<nb, 256, 0, stream>>>(cursor, offs, blocksums, n_nodes);
        scan_blocksums<<<1, 256, 0, stream>>>(blocksums, offs, nb, n_nodes);
        add_back<<<ab, 256, 0, stream>>>(offs, cursor, blocksums, n_nodes);
        scatter_csr<<<eb, 256, 0, stream>>>(src, dst, cursor, csr_src, n_edges);
        int gb = (n_nodes + 3) / 4;
        gather_fp32<<<gb, 256, 0, stream>>>(h, norm, eps, offs, csr_src, out, n_nodes);
    } else {
        gin_init<<<(pre_threads + 255) / 256, 256, 0, stream>>>(h, norm, eps, out, n_nodes);
        long long et = (long long)n_edges * 32;
        gin_edge<<<(int)((et + 255) / 256), 256, 0, stream>>>(h, norm, src, dst, out, n_edges);
    }
}